// Round 3
// baseline (244.721 us; speedup 1.0000x reference)
//
#include <hip/hip_runtime.h>

// wmc_loss: K=131072 rows, C=128 classes. One 32-lane half-wave per row,
// lane owns 4 consecutive columns (dwordx4, coalesced: wave64 = 1KiB/array).
//
// R3: R1/R2 were latency-bound (HBM 17%, VALU 35%) — each wave was a
// one-shot load-wait-compute-die, so memory was fed in bursts by wave churn.
// Now: 2048 blocks, each half-wave sweeps 8 rows with a depth-1 register
// double-buffer (prefetch next row's 4 loads before computing current row),
// keeping every wave's loads permanently in flight. Compute per row uses the
// R2 ballot tricks (Y rows are <=2-hot 0/1 masks): no butterfly reductions
// except the two softmax sums.

constexpr int KROWS       = 131072;
constexpr int CC          = 128;
constexpr int NB          = 2048;               // blocks
constexpr int ROWS_PER_IT = 8;                  // 256 thr / 32 lanes
constexpr int NIT         = KROWS / (NB * ROWS_PER_IT);  // = 8
#define THRF 9.2885e-30f

__device__ __forceinline__ float hredsumf(float v){
#pragma unroll
  for (int m = 16; m > 0; m >>= 1) v += __shfl_xor(v, m, 32);
  return v;
}

__device__ __forceinline__ float neglog_safe(float p){
  return (p > THRF) ? -__logf(p) : 0.0f;
}

__device__ __forceinline__ float sel4(float p0, float p1, float p2, float p3, int s){
  float lo = (s & 1) ? p1 : p0;
  float hi = (s & 1) ? p3 : p2;
  return (s & 2) ? hi : lo;
}

__device__ __forceinline__ float gatherP(float p0, float p1, float p2, float p3, int idx){
  float c = sel4(p0, p1, p2, p3, idx & 3);
  return __shfl(c, (idx >> 2) & 31, 32);
}

__device__ __forceinline__ float computeRow(
    float4 a1, float4 a2, int4 b1, int4 b2, bool hi)
{
  // softmaxes, no max-subtraction (scores ~N(0,1), exp-safe)
  float e10 = __expf(a1.x), e11 = __expf(a1.y), e12 = __expf(a1.z), e13 = __expf(a1.w);
  float e20 = __expf(a2.x), e21 = __expf(a2.y), e22 = __expf(a2.z), e23 = __expf(a2.w);
  float inv1 = 1.0f / hredsumf(e10 + e11 + e12 + e13);
  float inv2 = 1.0f / hredsumf(e20 + e21 + e22 + e23);
  float p10 = e10 * inv1, p11 = e11 * inv1, p12 = e12 * inv1, p13 = e13 * inv1;
  float p20 = e20 * inv2, p21 = e21 * inv2, p22 = e22 * inv2, p23 = e23 * inv2;

  // ballot-based lineage analysis (Y elements are 0/1)
  unsigned long long M1[4], M2[4];
  M1[0] = __ballot(b1.x); M1[1] = __ballot(b1.y); M1[2] = __ballot(b1.z); M1[3] = __ballot(b1.w);
  M2[0] = __ballot(b2.x); M2[1] = __ballot(b2.y); M2[2] = __ballot(b2.z); M2[3] = __ballot(b2.w);

  unsigned int h1[4], h2[4];
#pragma unroll
  for (int j = 0; j < 4; ++j) {
    h1[j] = hi ? (unsigned int)(M1[j] >> 32) : (unsigned int)M1[j];
    h2[j] = hi ? (unsigned int)(M2[j] >> 32) : (unsigned int)M2[j];
  }

  bool eq = (h1[0] == h2[0]) & (h1[1] == h2[1]) & (h1[2] == h2[2]) & (h1[3] == h2[3]);
  int srow = __popc(h1[0]) + __popc(h1[1]) + __popc(h1[2]) + __popc(h1[3]);

  int ia1 = 1 << 30, ib1 = -1, ia2 = 1 << 30, ib2 = -1;
#pragma unroll
  for (int j = 0; j < 4; ++j) {
    if (h1[j]) {
      ia1 = min(ia1, ((__ffs(h1[j]) - 1) << 2) + j);
      ib1 = max(ib1, ((31 - __clz(h1[j])) << 2) + j);
    }
    if (h2[j]) {
      ia2 = min(ia2, ((__ffs(h2[j]) - 1) << 2) + j);
      ib2 = max(ib2, ((31 - __clz(h2[j])) << 2) + j);
    }
  }

  float p1a1 = gatherP(p10, p11, p12, p13, ia1);
  float p1b1 = gatherP(p10, p11, p12, p13, ib1);
  float p1a2 = gatherP(p10, p11, p12, p13, ia2);
  float p1b2 = gatherP(p10, p11, p12, p13, ib2);
  float p2a1 = gatherP(p20, p21, p22, p23, ia1);
  float p2b1 = gatherP(p20, p21, p22, p23, ib1);
  float p2a2 = gatherP(p20, p21, p22, p23, ia2);
  float p2b2 = gatherP(p20, p21, p22, p23, ib2);

  // disjunctions: rows are <=2-hot, so prod(1-L*P) has <=2 factors
  float f1 = (ia1 != ib1) ? 1.0f : 0.0f;
  float f2 = (ia2 != ib2) ? 1.0f : 0.0f;
  float D11 = 1.0f - (1.0f - p1a1) * (1.0f - f1 * p1b1);
  float D12 = 1.0f - (1.0f - p2a1) * (1.0f - f1 * p2b1);
  float D21 = 1.0f - (1.0f - p1a2) * (1.0f - f2 * p1b2);
  float D22 = 1.0f - (1.0f - p2a2) * (1.0f - f2 * p2b2);

  float loss1 = neglog_safe(p1a1) + neglog_safe(p2a1);
  float prob2 = 1.0f - (1.0f - p1a1 * p2b1) * (1.0f - p1b1 * p2a1);
  float loss2 = neglog_safe(prob2);
  float probd = 1.0f - (1.0f - D11 * D22) * (1.0f - D21 * D12);
  float lossd = neglog_safe(probd);

  return (eq && srow == 1) ? loss1 : (eq && srow == 2) ? loss2 : lossd;
}

__global__ __launch_bounds__(256) void wmc_loss_kernel(
    const float* __restrict__ s1, const int* __restrict__ y1,
    const float* __restrict__ s2, const int* __restrict__ y2,
    float* __restrict__ out)
{
  const int hw   = threadIdx.x >> 5;        // half-wave id within block, 0..7
  const int lane = threadIdx.x & 31;
  const bool hi  = (threadIdx.x & 32) != 0;
  const int rowBase = blockIdx.x * (ROWS_PER_IT * NIT) + hw;  // 64 rows/block

  // preload row for iteration 0
  size_t base = (size_t)(rowBase) * CC;
  float4 A1 = ((const float4*)(s1 + base))[lane];
  float4 A2 = ((const float4*)(s2 + base))[lane];
  int4   B1 = ((const int4*)(y1 + base))[lane];
  int4   B2 = ((const int4*)(y2 + base))[lane];

#pragma unroll
  for (int it = 0; it < NIT; ++it) {
    const int row = rowBase + it * ROWS_PER_IT;

    // prefetch next row before touching (and thus waiting on) this row's data
    float4 nA1, nA2; int4 nB1, nB2;
    if (it + 1 < NIT) {
      const size_t nbase = (size_t)(row + ROWS_PER_IT) * CC;
      nA1 = ((const float4*)(s1 + nbase))[lane];
      nA2 = ((const float4*)(s2 + nbase))[lane];
      nB1 = ((const int4*)(y1 + nbase))[lane];
      nB2 = ((const int4*)(y2 + nbase))[lane];
    }

    float loss = computeRow(A1, A2, B1, B2, hi);
    if (lane == 0) out[row] = loss;

    if (it + 1 < NIT) { A1 = nA1; A2 = nA2; B1 = nB1; B2 = nB2; }
  }
}

extern "C" void kernel_launch(void* const* d_in, const int* in_sizes, int n_in,
                              void* d_out, int out_size, void* d_ws, size_t ws_size,
                              hipStream_t stream) {
  const float* s1 = (const float*)d_in[0];
  const int*   y1 = (const int*)d_in[1];
  const float* s2 = (const float*)d_in[2];
  const int*   y2 = (const int*)d_in[3];
  float* out = (float*)d_out;

  dim3 grid(NB), block(256);
  wmc_loss_kernel<<<grid, block, 0, stream>>>(s1, y1, s2, y2, out);
}

// Round 4
// 235.969 us; speedup vs baseline: 1.0371x; 1.0371x over previous
//
#include <hip/hip_runtime.h>

// wmc_loss: K=131072 rows, C=128 classes. One 32-lane half-wave per TWO rows,
// lane owns 4 consecutive columns of each (dwordx4, coalesced).
//
// R4: R1-R3 all plateau at ~2.8 TB/s effective read with VALUBusy ~30% and
// HBM ~17% — a latency-capacity equilibrium: each wave exposed only 4
// outstanding loads and ONE serial shfl-chain at a time. Now each half-wave
// processes 2 rows single-shot: 8 loads issued back-to-back (8 KiB/wave in
// flight) and two independent computeRow instances interleaved by the
// compiler (2x ILP on the ds_bpermute latency chains). No loop, no prefetch.

constexpr int KROWS = 131072;
constexpr int CC    = 128;
#define THRF 9.2885e-30f

__device__ __forceinline__ float hredsumf(float v){
#pragma unroll
  for (int m = 16; m > 0; m >>= 1) v += __shfl_xor(v, m, 32);
  return v;
}

__device__ __forceinline__ float neglog_safe(float p){
  return (p > THRF) ? -__logf(p) : 0.0f;
}

__device__ __forceinline__ float sel4(float p0, float p1, float p2, float p3, int s){
  float lo = (s & 1) ? p1 : p0;
  float hi = (s & 1) ? p3 : p2;
  return (s & 2) ? hi : lo;
}

__device__ __forceinline__ float gatherP(float p0, float p1, float p2, float p3, int idx){
  float c = sel4(p0, p1, p2, p3, idx & 3);
  return __shfl(c, (idx >> 2) & 31, 32);
}

__device__ __forceinline__ float computeRow(
    float4 a1, float4 a2, int4 b1, int4 b2, bool hi)
{
  // softmaxes, no max-subtraction (scores ~N(0,1), exp-safe)
  float e10 = __expf(a1.x), e11 = __expf(a1.y), e12 = __expf(a1.z), e13 = __expf(a1.w);
  float e20 = __expf(a2.x), e21 = __expf(a2.y), e22 = __expf(a2.z), e23 = __expf(a2.w);
  float inv1 = 1.0f / hredsumf(e10 + e11 + e12 + e13);
  float inv2 = 1.0f / hredsumf(e20 + e21 + e22 + e23);
  float p10 = e10 * inv1, p11 = e11 * inv1, p12 = e12 * inv1, p13 = e13 * inv1;
  float p20 = e20 * inv2, p21 = e21 * inv2, p22 = e22 * inv2, p23 = e23 * inv2;

  // ballot-based lineage analysis (Y elements are 0/1, rows <=2-hot)
  unsigned long long M1[4], M2[4];
  M1[0] = __ballot(b1.x); M1[1] = __ballot(b1.y); M1[2] = __ballot(b1.z); M1[3] = __ballot(b1.w);
  M2[0] = __ballot(b2.x); M2[1] = __ballot(b2.y); M2[2] = __ballot(b2.z); M2[3] = __ballot(b2.w);

  unsigned int h1[4], h2[4];
#pragma unroll
  for (int j = 0; j < 4; ++j) {
    h1[j] = hi ? (unsigned int)(M1[j] >> 32) : (unsigned int)M1[j];
    h2[j] = hi ? (unsigned int)(M2[j] >> 32) : (unsigned int)M2[j];
  }

  bool eq = (h1[0] == h2[0]) & (h1[1] == h2[1]) & (h1[2] == h2[2]) & (h1[3] == h2[3]);
  int srow = __popc(h1[0]) + __popc(h1[1]) + __popc(h1[2]) + __popc(h1[3]);

  int ia1 = 1 << 30, ib1 = -1, ia2 = 1 << 30, ib2 = -1;
#pragma unroll
  for (int j = 0; j < 4; ++j) {
    if (h1[j]) {
      ia1 = min(ia1, ((__ffs(h1[j]) - 1) << 2) + j);
      ib1 = max(ib1, ((31 - __clz(h1[j])) << 2) + j);
    }
    if (h2[j]) {
      ia2 = min(ia2, ((__ffs(h2[j]) - 1) << 2) + j);
      ib2 = max(ib2, ((31 - __clz(h2[j])) << 2) + j);
    }
  }

  float p1a1 = gatherP(p10, p11, p12, p13, ia1);
  float p1b1 = gatherP(p10, p11, p12, p13, ib1);
  float p1a2 = gatherP(p10, p11, p12, p13, ia2);
  float p1b2 = gatherP(p10, p11, p12, p13, ib2);
  float p2a1 = gatherP(p20, p21, p22, p23, ia1);
  float p2b1 = gatherP(p20, p21, p22, p23, ib1);
  float p2a2 = gatherP(p20, p21, p22, p23, ia2);
  float p2b2 = gatherP(p20, p21, p22, p23, ib2);

  // disjunctions: rows are <=2-hot, so prod(1-L*P) has <=2 factors
  float f1 = (ia1 != ib1) ? 1.0f : 0.0f;
  float f2 = (ia2 != ib2) ? 1.0f : 0.0f;
  float D11 = 1.0f - (1.0f - p1a1) * (1.0f - f1 * p1b1);
  float D12 = 1.0f - (1.0f - p2a1) * (1.0f - f1 * p2b1);
  float D21 = 1.0f - (1.0f - p1a2) * (1.0f - f2 * p1b2);
  float D22 = 1.0f - (1.0f - p2a2) * (1.0f - f2 * p2b2);

  float loss1 = neglog_safe(p1a1) + neglog_safe(p2a1);
  float prob2 = 1.0f - (1.0f - p1a1 * p2b1) * (1.0f - p1b1 * p2a1);
  float loss2 = neglog_safe(prob2);
  float probd = 1.0f - (1.0f - D11 * D22) * (1.0f - D21 * D12);
  float lossd = neglog_safe(probd);

  return (eq && srow == 1) ? loss1 : (eq && srow == 2) ? loss2 : lossd;
}

__global__ __launch_bounds__(256) void wmc_loss_kernel(
    const float* __restrict__ s1, const int* __restrict__ y1,
    const float* __restrict__ s2, const int* __restrict__ y2,
    float* __restrict__ out)
{
  const int hw   = threadIdx.x >> 5;        // half-wave id, 0..7
  const int lane = threadIdx.x & 31;
  const bool hi  = (threadIdx.x & 32) != 0;
  // block covers 16 consecutive rows; half-wave hw owns rows 2hw, 2hw+1
  const int row0 = blockIdx.x * 16 + hw * 2;

  const size_t base0 = (size_t)row0 * CC;
  const size_t base1 = base0 + CC;

  // issue all 8 loads back-to-back: 8 KiB per wave in flight
  const float4 A10 = ((const float4*)(s1 + base0))[lane];
  const float4 A20 = ((const float4*)(s2 + base0))[lane];
  const int4   B10 = ((const int4*)(y1 + base0))[lane];
  const int4   B20 = ((const int4*)(y2 + base0))[lane];
  const float4 A11 = ((const float4*)(s1 + base1))[lane];
  const float4 A21 = ((const float4*)(s2 + base1))[lane];
  const int4   B11 = ((const int4*)(y1 + base1))[lane];
  const int4   B21 = ((const int4*)(y2 + base1))[lane];

  // two independent instances — compiler interleaves (2x chain ILP)
  float l0 = computeRow(A10, A20, B10, B20, hi);
  float l1 = computeRow(A11, A21, B11, B21, hi);

  if (lane == 0) {
    float2 o; o.x = l0; o.y = l1;
    ((float2*)(out + row0))[0] = o;   // row0 is even -> 8B aligned
  }
}

extern "C" void kernel_launch(void* const* d_in, const int* in_sizes, int n_in,
                              void* d_out, int out_size, void* d_ws, size_t ws_size,
                              hipStream_t stream) {
  const float* s1 = (const float*)d_in[0];
  const int*   y1 = (const int*)d_in[1];
  const float* s2 = (const float*)d_in[2];
  const int*   y2 = (const int*)d_in[3];
  float* out = (float*)d_out;

  dim3 grid(KROWS / 16), block(256);  // 8192 blocks, 16 rows/block
  wmc_loss_kernel<<<grid, block, 0, stream>>>(s1, y1, s2, y2, out);
}

// Round 6
// 210.049 us; speedup vs baseline: 1.1651x; 1.1234x over previous
//
#include <hip/hip_runtime.h>

// wmc_loss: K=131072 rows, C=128 classes. One 32-lane half-wave per TWO rows,
// lane owns 4 consecutive columns of each (dwordx4, coalesced).
//
// R6 (= R5 fixed): R1-R4 invariantly ~96 µs = 2.8 TB/s effective read = 227
// cy per wave64 VMEM instr per CU (~= L2-hit latency) with VALU/LDS/occupancy
// all slack — consistent with per-CU L1-path serialization on stream-once
// data. Change ONE thing vs R4: loads/store are non-temporal. R5 failed to
// compile because __builtin_nontemporal_* rejects HIP_vector_type; use
// clang-native ext_vector_type instead (same layout & codegen + nt flag).

constexpr int KROWS = 131072;
constexpr int CC    = 128;
#define THRF 9.2885e-30f

typedef float  f32x4 __attribute__((ext_vector_type(4)));
typedef int    i32x4 __attribute__((ext_vector_type(4)));
typedef float  f32x2 __attribute__((ext_vector_type(2)));

__device__ __forceinline__ float hredsumf(float v){
#pragma unroll
  for (int m = 16; m > 0; m >>= 1) v += __shfl_xor(v, m, 32);
  return v;
}

__device__ __forceinline__ float neglog_safe(float p){
  return (p > THRF) ? -__logf(p) : 0.0f;
}

__device__ __forceinline__ float sel4(float p0, float p1, float p2, float p3, int s){
  float lo = (s & 1) ? p1 : p0;
  float hi = (s & 1) ? p3 : p2;
  return (s & 2) ? hi : lo;
}

__device__ __forceinline__ float gatherP(float p0, float p1, float p2, float p3, int idx){
  float c = sel4(p0, p1, p2, p3, idx & 3);
  return __shfl(c, (idx >> 2) & 31, 32);
}

__device__ __forceinline__ float computeRow(
    f32x4 a1, f32x4 a2, i32x4 b1, i32x4 b2, bool hi)
{
  // softmaxes, no max-subtraction (scores ~N(0,1), exp-safe)
  float e10 = __expf(a1.x), e11 = __expf(a1.y), e12 = __expf(a1.z), e13 = __expf(a1.w);
  float e20 = __expf(a2.x), e21 = __expf(a2.y), e22 = __expf(a2.z), e23 = __expf(a2.w);
  float inv1 = 1.0f / hredsumf(e10 + e11 + e12 + e13);
  float inv2 = 1.0f / hredsumf(e20 + e21 + e22 + e23);
  float p10 = e10 * inv1, p11 = e11 * inv1, p12 = e12 * inv1, p13 = e13 * inv1;
  float p20 = e20 * inv2, p21 = e21 * inv2, p22 = e22 * inv2, p23 = e23 * inv2;

  // ballot-based lineage analysis (Y elements are 0/1, rows <=2-hot)
  unsigned long long M1[4], M2[4];
  M1[0] = __ballot(b1.x); M1[1] = __ballot(b1.y); M1[2] = __ballot(b1.z); M1[3] = __ballot(b1.w);
  M2[0] = __ballot(b2.x); M2[1] = __ballot(b2.y); M2[2] = __ballot(b2.z); M2[3] = __ballot(b2.w);

  unsigned int h1[4], h2[4];
#pragma unroll
  for (int j = 0; j < 4; ++j) {
    h1[j] = hi ? (unsigned int)(M1[j] >> 32) : (unsigned int)M1[j];
    h2[j] = hi ? (unsigned int)(M2[j] >> 32) : (unsigned int)M2[j];
  }

  bool eq = (h1[0] == h2[0]) & (h1[1] == h2[1]) & (h1[2] == h2[2]) & (h1[3] == h2[3]);
  int srow = __popc(h1[0]) + __popc(h1[1]) + __popc(h1[2]) + __popc(h1[3]);

  int ia1 = 1 << 30, ib1 = -1, ia2 = 1 << 30, ib2 = -1;
#pragma unroll
  for (int j = 0; j < 4; ++j) {
    if (h1[j]) {
      ia1 = min(ia1, ((__ffs(h1[j]) - 1) << 2) + j);
      ib1 = max(ib1, ((31 - __clz(h1[j])) << 2) + j);
    }
    if (h2[j]) {
      ia2 = min(ia2, ((__ffs(h2[j]) - 1) << 2) + j);
      ib2 = max(ib2, ((31 - __clz(h2[j])) << 2) + j);
    }
  }

  float p1a1 = gatherP(p10, p11, p12, p13, ia1);
  float p1b1 = gatherP(p10, p11, p12, p13, ib1);
  float p1a2 = gatherP(p10, p11, p12, p13, ia2);
  float p1b2 = gatherP(p10, p11, p12, p13, ib2);
  float p2a1 = gatherP(p20, p21, p22, p23, ia1);
  float p2b1 = gatherP(p20, p21, p22, p23, ib1);
  float p2a2 = gatherP(p20, p21, p22, p23, ia2);
  float p2b2 = gatherP(p20, p21, p22, p23, ib2);

  // disjunctions: rows are <=2-hot, so prod(1-L*P) has <=2 factors
  float f1 = (ia1 != ib1) ? 1.0f : 0.0f;
  float f2 = (ia2 != ib2) ? 1.0f : 0.0f;
  float D11 = 1.0f - (1.0f - p1a1) * (1.0f - f1 * p1b1);
  float D12 = 1.0f - (1.0f - p2a1) * (1.0f - f1 * p2b1);
  float D21 = 1.0f - (1.0f - p1a2) * (1.0f - f2 * p1b2);
  float D22 = 1.0f - (1.0f - p2a2) * (1.0f - f2 * p2b2);

  float loss1 = neglog_safe(p1a1) + neglog_safe(p2a1);
  float prob2 = 1.0f - (1.0f - p1a1 * p2b1) * (1.0f - p1b1 * p2a1);
  float loss2 = neglog_safe(prob2);
  float probd = 1.0f - (1.0f - D11 * D22) * (1.0f - D21 * D12);
  float lossd = neglog_safe(probd);

  return (eq && srow == 1) ? loss1 : (eq && srow == 2) ? loss2 : lossd;
}

__global__ __launch_bounds__(256) void wmc_loss_kernel(
    const float* __restrict__ s1, const int* __restrict__ y1,
    const float* __restrict__ s2, const int* __restrict__ y2,
    float* __restrict__ out)
{
  const int hw   = threadIdx.x >> 5;        // half-wave id, 0..7
  const int lane = threadIdx.x & 31;
  const bool hi  = (threadIdx.x & 32) != 0;
  // block covers 16 consecutive rows; half-wave hw owns rows 2hw, 2hw+1
  const int row0 = blockIdx.x * 16 + hw * 2;

  const size_t base0 = (size_t)row0 * CC;
  const size_t base1 = base0 + CC;

  // issue all 8 loads back-to-back, non-temporal (stream-once, bypass L1)
  const f32x4 A10 = __builtin_nontemporal_load(((const f32x4*)(s1 + base0)) + lane);
  const f32x4 A20 = __builtin_nontemporal_load(((const f32x4*)(s2 + base0)) + lane);
  const i32x4 B10 = __builtin_nontemporal_load(((const i32x4*)(y1 + base0)) + lane);
  const i32x4 B20 = __builtin_nontemporal_load(((const i32x4*)(y2 + base0)) + lane);
  const f32x4 A11 = __builtin_nontemporal_load(((const f32x4*)(s1 + base1)) + lane);
  const f32x4 A21 = __builtin_nontemporal_load(((const f32x4*)(s2 + base1)) + lane);
  const i32x4 B11 = __builtin_nontemporal_load(((const i32x4*)(y1 + base1)) + lane);
  const i32x4 B21 = __builtin_nontemporal_load(((const i32x4*)(y2 + base1)) + lane);

  // two independent instances — compiler interleaves (2x chain ILP)
  float l0 = computeRow(A10, A20, B10, B20, hi);
  float l1 = computeRow(A11, A21, B11, B21, hi);

  if (lane == 0) {
    f32x2 o; o.x = l0; o.y = l1;
    __builtin_nontemporal_store(o, (f32x2*)(out + row0));  // row0 even -> 8B aligned
  }
}

extern "C" void kernel_launch(void* const* d_in, const int* in_sizes, int n_in,
                              void* d_out, int out_size, void* d_ws, size_t ws_size,
                              hipStream_t stream) {
  const float* s1 = (const float*)d_in[0];
  const int*   y1 = (const int*)d_in[1];
  const float* s2 = (const float*)d_in[2];
  const int*   y2 = (const int*)d_in[3];
  float* out = (float*)d_out;

  dim3 grid(KROWS / 16), block(256);  // 8192 blocks, 16 rows/block
  wmc_loss_kernel<<<grid, block, 0, stream>>>(s1, y1, s2, y2, out);
}

// Round 7
// 209.087 us; speedup vs baseline: 1.1704x; 1.0046x over previous
//
#include <hip/hip_runtime.h>

// wmc_loss: K=131072 rows, C=128 classes. One 32-lane half-wave per TWO rows,
// lane owns 4 consecutive columns of each (nt dwordx4, coalesced).
//
// R7: R6 (nt loads) confirmed the L1-bypass theory: 96.9 -> 48.0 µs, HBM 35%,
// VALUBusy 62% -> VALU is now the wall (~275 VALU instrs/row of ballot/gather/
// case machinery). Algebraic collapse: with u,v = first/last column of the
// UNION mask Y1|Y2, all three supported cases reduce to
//   prob = (u==v) ? p1u*p2u : 1-(1-p1u*p2v)(1-p1v*p2u);  loss = safe_neglog(prob)
// (equal-1-hot: product-of-probs; equal-2-hot and disjoint-1-hots expand to the
// same symmetric expression under either ordering). 4 ballots instead of 8,
// 4 gathers instead of 8, one log instead of three, no eq/popcount.
// Memory structure identical to R6 for attribution.

constexpr int KROWS = 131072;
constexpr int CC    = 128;
#define THRF 9.2885e-30f

typedef float  f32x4 __attribute__((ext_vector_type(4)));
typedef int    i32x4 __attribute__((ext_vector_type(4)));
typedef float  f32x2 __attribute__((ext_vector_type(2)));

__device__ __forceinline__ float hredsumf(float v){
#pragma unroll
  for (int m = 16; m > 0; m >>= 1) v += __shfl_xor(v, m, 32);
  return v;
}

__device__ __forceinline__ float sel4(float p0, float p1, float p2, float p3, int s){
  float lo = (s & 1) ? p1 : p0;
  float hi = (s & 1) ? p3 : p2;
  return (s & 2) ? hi : lo;
}

// broadcast value[idx] (column idx, half-wave-uniform) from its owner lane
__device__ __forceinline__ float gatherP(float p0, float p1, float p2, float p3, int idx){
  float c = sel4(p0, p1, p2, p3, idx & 3);
  return __shfl(c, (idx >> 2) & 31, 32);
}

__device__ __forceinline__ float computeRow(
    f32x4 a1, f32x4 a2, i32x4 b1, i32x4 b2, bool hi)
{
  // softmax exps, no max-subtraction (scores ~N(0,1), exp-safe)
  float e10 = __expf(a1.x), e11 = __expf(a1.y), e12 = __expf(a1.z), e13 = __expf(a1.w);
  float e20 = __expf(a2.x), e21 = __expf(a2.y), e22 = __expf(a2.z), e23 = __expf(a2.w);
  float inv1 = 1.0f / hredsumf(e10 + e11 + e12 + e13);
  float inv2 = 1.0f / hredsumf(e20 + e21 + e22 + e23);

  // union-mask ballots (Y elements are 0/1; union has 1 or 2 set columns)
  unsigned long long M0 = __ballot((b1.x | b2.x) != 0);
  unsigned long long M1 = __ballot((b1.y | b2.y) != 0);
  unsigned long long M2 = __ballot((b1.z | b2.z) != 0);
  unsigned long long M3 = __ballot((b1.w | b2.w) != 0);

  unsigned int h[4];
  h[0] = hi ? (unsigned int)(M0 >> 32) : (unsigned int)M0;
  h[1] = hi ? (unsigned int)(M1 >> 32) : (unsigned int)M1;
  h[2] = hi ? (unsigned int)(M2 >> 32) : (unsigned int)M2;
  h[3] = hi ? (unsigned int)(M3 >> 32) : (unsigned int)M3;

  // first (u) and last (v) set column of the union; column = lane*4 + j
  int u = 1 << 30, v = -1;
#pragma unroll
  for (int j = 0; j < 4; ++j) {
    if (h[j]) {
      u = min(u, ((__ffs(h[j]) - 1) << 2) + j);
      v = max(v, ((31 - __clz(h[j])) << 2) + j);
    }
  }

  // gather raw exps at u, v; scale by softmax denominators
  float p1u = gatherP(e10, e11, e12, e13, u) * inv1;
  float p1v = gatherP(e10, e11, e12, e13, v) * inv1;
  float p2u = gatherP(e20, e21, e22, e23, u) * inv2;
  float p2v = gatherP(e20, e21, e22, e23, v) * inv2;

  float x = p1u * p2v;
  float y = p1v * p2u;
  float prob = (u == v) ? x : 1.0f - (1.0f - x) * (1.0f - y);
  return (prob > THRF) ? -__logf(prob) : 0.0f;
}

__global__ __launch_bounds__(256) void wmc_loss_kernel(
    const float* __restrict__ s1, const int* __restrict__ y1,
    const float* __restrict__ s2, const int* __restrict__ y2,
    float* __restrict__ out)
{
  const int hw   = threadIdx.x >> 5;        // half-wave id, 0..7
  const int lane = threadIdx.x & 31;
  const bool hi  = (threadIdx.x & 32) != 0;
  // block covers 16 consecutive rows; half-wave hw owns rows 2hw, 2hw+1
  const int row0 = blockIdx.x * 16 + hw * 2;

  const size_t base0 = (size_t)row0 * CC;
  const size_t base1 = base0 + CC;

  // 8 loads back-to-back, non-temporal (stream-once, bypass L1)
  const f32x4 A10 = __builtin_nontemporal_load(((const f32x4*)(s1 + base0)) + lane);
  const f32x4 A20 = __builtin_nontemporal_load(((const f32x4*)(s2 + base0)) + lane);
  const i32x4 B10 = __builtin_nontemporal_load(((const i32x4*)(y1 + base0)) + lane);
  const i32x4 B20 = __builtin_nontemporal_load(((const i32x4*)(y2 + base0)) + lane);
  const f32x4 A11 = __builtin_nontemporal_load(((const f32x4*)(s1 + base1)) + lane);
  const f32x4 A21 = __builtin_nontemporal_load(((const f32x4*)(s2 + base1)) + lane);
  const i32x4 B11 = __builtin_nontemporal_load(((const i32x4*)(y1 + base1)) + lane);
  const i32x4 B21 = __builtin_nontemporal_load(((const i32x4*)(y2 + base1)) + lane);

  // two independent instances — compiler interleaves (2x chain ILP)
  float l0 = computeRow(A10, A20, B10, B20, hi);
  float l1 = computeRow(A11, A21, B11, B21, hi);

  if (lane == 0) {
    f32x2 o; o.x = l0; o.y = l1;
    __builtin_nontemporal_store(o, (f32x2*)(out + row0));  // row0 even -> 8B aligned
  }
}

extern "C" void kernel_launch(void* const* d_in, const int* in_sizes, int n_in,
                              void* d_out, int out_size, void* d_ws, size_t ws_size,
                              hipStream_t stream) {
  const float* s1 = (const float*)d_in[0];
  const int*   y1 = (const int*)d_in[1];
  const float* s2 = (const float*)d_in[2];
  const int*   y2 = (const int*)d_in[3];
  float* out = (float*)d_out;

  dim3 grid(KROWS / 16), block(256);  // 8192 blocks, 16 rows/block
  wmc_loss_kernel<<<grid, block, 0, stream>>>(s1, y1, s2, y2, out);
}